// Round 7
// baseline (367.672 us; speedup 1.0000x reference)
//
#include <hip/hip_runtime.h>
#include <hip/hip_bf16.h>
#include <cstdint>
#include <math.h>

#define NB 4
#define NN 512
#define DH 128
#define NHEADS 8
#define NHID 16
#define SLOPE 0.2f
#define ITILE 64
#define SENTINEL -1e30f

// ---- one-time adjacency bitmask pack: adjb[row][w] bit k = adj[row][w*32+k] ----
__global__ __launch_bounds__(256) void pack_adj_kernel(
    const int* __restrict__ adj, uint32_t* __restrict__ adjb)
{
    const int t   = threadIdx.x;
    const int row = blockIdx.x * 16 + (t >> 4);
    const int w   = t & 15;
    const int4* p = (const int4*)(adj + (size_t)row * NN + w * 32);
    uint32_t m = 0;
#pragma unroll
    for (int c = 0; c < 8; ++c) {
        const int4 v = p[c];
        m |= (v.x != 0 ? 1u : 0u) << (c * 4 + 0);
        m |= (v.y != 0 ? 1u : 0u) << (c * 4 + 1);
        m |= (v.z != 0 ? 1u : 0u) << (c * 4 + 2);
        m |= (v.w != 0 ? 1u : 0u) << (c * 4 + 3);
    }
    adjb[(size_t)row * 16 + w] = m;
}

// ---- projection: 8 rows/block, outputs HEAD-MAJOR gl/gr [b*8+hh][512][16] ----
__global__ __launch_bounds__(256) void proj_kernel(
    const float* __restrict__ h, const float* __restrict__ X,
    const float* __restrict__ Win,
    const float* __restrict__ Wl, const float* __restrict__ Wr,
    float* __restrict__ gl, float* __restrict__ gr)
{
    __shared__ __align__(16) float s_h[8][DH];
    const int bn0 = blockIdx.x * 8;
    const int b   = bn0 >> 9;
    const int n0  = bn0 & 511;
    const int t   = threadIdx.x;

    if (X) {
        if (t < DH) {
            const float w0 = Win[t], w1 = Win[DH + t];
#pragma unroll
            for (int r = 0; r < 8; ++r) {
                const float x0 = X[(bn0 + r) * 2 + 0];
                const float x1 = X[(bn0 + r) * 2 + 1];
                s_h[r][t] = x0 * w0 + x1 * w1;
            }
        }
    } else {
        for (int idx = t; idx < 8 * DH; idx += 256)
            s_h[idx >> 7][idx & 127] = h[(size_t)bn0 * DH + idx];
    }
    __syncthreads();

    const float* W = (t < DH) ? Wl : Wr;   // wave-uniform split
    float*       g = (t < DH) ? gl : gr;
    const int f128 = t & 127;
    float acc[8] = {};
    for (int k = 0; k < DH; k += 4) {
        const float w0 = W[(k + 0) * DH + f128];
        const float w1 = W[(k + 1) * DH + f128];
        const float w2 = W[(k + 2) * DH + f128];
        const float w3 = W[(k + 3) * DH + f128];
#pragma unroll
        for (int r = 0; r < 8; ++r) {
            const float4 hv = *(const float4*)&s_h[r][k];
            acc[r] += hv.x * w0 + hv.y * w1 + hv.z * w2 + hv.w * w3;
        }
    }
    const int hh = f128 >> 4, f = f128 & 15;
    float* dst = g + ((size_t)(b * NHEADS + hh) * NN + n0) * NHID + f;
#pragma unroll
    for (int r = 0; r < 8; ++r)
        dst[r * NHID] = acc[r];
}

// ---- flash-style attention: one block per (b, head, 64-row i-tile) ----
// 512 threads: il = t&31 (thread owns rows il and il+32), js = t>>5 (32-j slice).
// Each LDS j-read feeds TWO query rows (halves LDS-pipe demand vs R5).
// Two-pass softmax fully in registers (sc[32] per row), no online rescale.
__global__ __launch_bounds__(512) void attn_kernel(
    const float* __restrict__ gl, const float* __restrict__ gr,
    const uint32_t* __restrict__ adjb, const float* __restrict__ a_vec,
    float* __restrict__ h_out,
    const float* __restrict__ Wout, float* __restrict__ out)
{
    __shared__ __align__(16) float smem[19648];   // 78592 B
    float* s_gl  = smem;                // [512*16] = 8192
    float* s_gr  = smem + 8192;         // [512*16] = 8192
    float* s_acc = smem;                // alias (staging dead), [16*64*17]=17408
    float* s_m   = smem + 17408;        // [16*66]
    float* s_l   = smem + 18464;        // [16*66]
    float* s_M   = smem + 19520;        // [64]
    float* s_inv = smem + 19584;        // [64]

    const int blk = blockIdx.x;         // 256 = (b*8+hh)*8 + it
    const int it  = blk & 7;
    const int bh  = blk >> 3;
    const int b   = bh >> 3;
    const int hh  = bh & 7;
    const int i0  = it * ITILE;
    const int t   = threadIdx.x;
    const int il  = t & 31;
    const int js  = t >> 5;
    const int jbase = js * 32;

    {   // stage head planes: 2048 float4 each (512 rows x 16 fp32), coalesced
        const float4* pgl = (const float4*)(gl + (size_t)bh * NN * NHID);
        const float4* pgr = (const float4*)(gr + (size_t)bh * NN * NHID);
        float4* dl = (float4*)s_gl;
        float4* dr = (float4*)s_gr;
#pragma unroll
        for (int k = 0; k < 4; ++k) {           // 4 * 512 threads = 2048 float4
            dl[k * 512 + t] = pgl[k * 512 + t];
            dr[k * 512 + t] = pgr[k * 512 + t];
        }
    }
    const float4* a_g = (const float4*)a_vec;
    const float4 a4[4] = { a_g[0], a_g[1], a_g[2], a_g[3] };
    const uint32_t mask0 = adjb[((size_t)(b * NN + i0 + il))      * 16 + js];
    const uint32_t mask1 = adjb[((size_t)(b * NN + i0 + il + 32)) * 16 + js];
    __syncthreads();

    float gri0[16], gri1[16];
    {
        const float4* p0 = (const float4*)(s_gr + (i0 + il) * NHID);
        const float4* p1 = (const float4*)(s_gr + (i0 + il + 32) * NHID);
#pragma unroll
        for (int q = 0; q < 4; ++q) {
            const float4 v0 = p0[q], v1 = p1[q];
            gri0[4*q] = v0.x; gri0[4*q+1] = v0.y; gri0[4*q+2] = v0.z; gri0[4*q+3] = v0.w;
            gri1[4*q] = v1.x; gri1[4*q+1] = v1.y; gri1[4*q+2] = v1.z; gri1[4*q+3] = v1.w;
        }
    }

    // ---- pass 1: scores for 2 rows, all in registers ----
    float sc0[32], sc1[32];
#pragma unroll
    for (int jj = 0; jj < 32; ++jj) {
        const float4* pg = (const float4*)(s_gl + (jbase + jj) * NHID);
        float s0 = 0.f, s1 = 0.f;
#pragma unroll
        for (int q = 0; q < 4; ++q) {
            const float4 g = pg[q];     // half-wave-uniform -> broadcast
            const float4 av = a4[q];
            float v;
            v = g.x + gri0[4*q+0]; v = fmaxf(v, SLOPE * v); s0 += v * av.x;
            v = g.y + gri0[4*q+1]; v = fmaxf(v, SLOPE * v); s0 += v * av.y;
            v = g.z + gri0[4*q+2]; v = fmaxf(v, SLOPE * v); s0 += v * av.z;
            v = g.w + gri0[4*q+3]; v = fmaxf(v, SLOPE * v); s0 += v * av.w;
            v = g.x + gri1[4*q+0]; v = fmaxf(v, SLOPE * v); s1 += v * av.x;
            v = g.y + gri1[4*q+1]; v = fmaxf(v, SLOPE * v); s1 += v * av.y;
            v = g.z + gri1[4*q+2]; v = fmaxf(v, SLOPE * v); s1 += v * av.z;
            v = g.w + gri1[4*q+3]; v = fmaxf(v, SLOPE * v); s1 += v * av.w;
        }
        sc0[jj] = ((mask0 >> jj) & 1u) ? s0 : SENTINEL;
        sc1[jj] = ((mask1 >> jj) & 1u) ? s1 : SENTINEL;
    }
    float m0 = SENTINEL, m1 = SENTINEL;
#pragma unroll
    for (int jj = 0; jj < 32; ++jj) { m0 = fmaxf(m0, sc0[jj]); m1 = fmaxf(m1, sc1[jj]); }

    // ---- pass 2: exp + aggregate ----
    float acc0[16] = {}, acc1[16] = {};
    float l0 = 0.f, l1 = 0.f;
#pragma unroll
    for (int jj = 0; jj < 32; ++jj) {
        const float p0 = __expf(sc0[jj] - m0);    // masked -> exp(-huge) = 0
        const float p1 = __expf(sc1[jj] - m1);
        l0 += p0; l1 += p1;
        const float4* pg = (const float4*)(s_gr + (jbase + jj) * NHID);
#pragma unroll
        for (int q = 0; q < 4; ++q) {
            const float4 g = pg[q];     // broadcast
            acc0[4*q+0] += p0 * g.x; acc0[4*q+1] += p0 * g.y;
            acc0[4*q+2] += p0 * g.z; acc0[4*q+3] += p0 * g.w;
            acc1[4*q+0] += p1 * g.x; acc1[4*q+1] += p1 * g.y;
            acc1[4*q+2] += p1 * g.z; acc1[4*q+3] += p1 * g.w;
        }
    }
    s_m[js * 66 + il]      = m0;  s_l[js * 66 + il]      = l0;
    s_m[js * 66 + il + 32] = m1;  s_l[js * 66 + il + 32] = l1;
    __syncthreads();                      // all staging reads retired here

    if (t < 64) {                         // per-i global max + denom
        float M = SENTINEL;
#pragma unroll
        for (int k = 0; k < 16; ++k) M = fmaxf(M, s_m[k * 66 + t]);
        float L = 0.f;
#pragma unroll
        for (int k = 0; k < 16; ++k) L += s_l[k * 66 + t] * __expf(s_m[k * 66 + t] - M);
        s_M[t]   = M;
        s_inv[t] = 1.f / L;
    }
    __syncthreads();

    {   // scaled partials into aliased scratch (stride 17 -> conflict-free)
        const float f0s = __expf(m0 - s_M[il])      * s_inv[il];       // all-masked slice -> 0
        const float f1s = __expf(m1 - s_M[il + 32]) * s_inv[il + 32];
        float* d0 = s_acc + (js * 64 + il) * 17;
        float* d1 = s_acc + (js * 64 + il + 32) * 17;
#pragma unroll
        for (int f = 0; f < 16; ++f) { d0[f] = acc0[f] * f0s; d1[f] = acc1[f] * f1s; }
    }
    __syncthreads();

    {   // final reduce: thread (i = t>>4 [+32], f = t&15)
        const int f = t & 15;
#pragma unroll
        for (int half = 0; half < 2; ++half) {
            const int i = (t >> 4) + half * 32;
            float o = 0.f;
#pragma unroll
            for (int k = 0; k < 16; ++k) o += s_acc[(k * 64 + i) * 17 + f];
            if (Wout) {                   // fused h @ W_out partial per head
                float v = o * Wout[hh * NHID + f];
#pragma unroll
                for (int off = 8; off; off >>= 1) v += __shfl_xor(v, off);
                if (f == 0) atomicAdd(out + b * NN + i0 + i, v);
            } else {
                h_out[((size_t)(b * NN + i0 + i)) * DH + hh * NHID + f] = o;
            }
        }
    }
}

extern "C" void kernel_launch(void* const* d_in, const int* in_sizes, int n_in,
                              void* d_out, int out_size, void* d_ws, size_t ws_size,
                              hipStream_t stream) {
    const float* X    = (const float*)d_in[0];   // [4,512,2]
    const int*   adj  = (const int*)  d_in[1];   // [4,512,512]
    const float* Win  = (const float*)d_in[2];   // [2,128]
    const float* Wl   = (const float*)d_in[3];   // [3,128,128]
    const float* Wr   = (const float*)d_in[4];   // [3,128,128]
    const float* Aa   = (const float*)d_in[5];   // [3,16]
    const float* Wout = (const float*)d_in[6];   // [128,1]
    float* out = (float*)d_out;                  // [4,512] fp32

    float*    ws   = (float*)d_ws;
    float*    h    = ws;                 // 1 MB
    float*    gl   = ws + 262144;        // 1 MB (head-major)
    float*    gr   = ws + 524288;        // 1 MB (head-major)
    uint32_t* adjb = (uint32_t*)(ws + 786432);   // 128 KB

    pack_adj_kernel<<<NB * NN / 16, 256, 0, stream>>>(adj, adjb);
    hipMemsetAsync(out, 0, (size_t)out_size * sizeof(float), stream);  // atomic target

    for (int l = 0; l < 3; ++l) {
        proj_kernel<<<NB * NN / 8, 256, 0, stream>>>(
            h, (l == 0) ? X : nullptr, Win,
            Wl + (size_t)l * DH * DH, Wr + (size_t)l * DH * DH, gl, gr);
        const bool last = (l == 2);
        attn_kernel<<<NB * NHEADS * (NN / ITILE), 512, 0, stream>>>(
            gl, gr, adjb, Aa + l * NHID, h,
            last ? Wout : nullptr, out);
    }
}

// Round 8
// 185.820 us; speedup vs baseline: 1.9786x; 1.9786x over previous
//
#include <hip/hip_runtime.h>
#include <hip/hip_bf16.h>
#include <cstdint>
#include <math.h>

#define NB 4
#define NN 512
#define DH 128
#define NHEADS 8
#define NHID 16
#define SLOPE 0.2f
#define ITILE 64
#define SENTINEL -1e30f

// ---- one-time adjacency bitmask pack: adjb[row][w] bit k = adj[row][w*32+k] ----
__global__ __launch_bounds__(256) void pack_adj_kernel(
    const int* __restrict__ adj, uint32_t* __restrict__ adjb)
{
    const int t   = threadIdx.x;
    const int row = blockIdx.x * 16 + (t >> 4);
    const int w   = t & 15;
    const int4* p = (const int4*)(adj + (size_t)row * NN + w * 32);
    uint32_t m = 0;
#pragma unroll
    for (int c = 0; c < 8; ++c) {
        const int4 v = p[c];
        m |= (v.x != 0 ? 1u : 0u) << (c * 4 + 0);
        m |= (v.y != 0 ? 1u : 0u) << (c * 4 + 1);
        m |= (v.z != 0 ? 1u : 0u) << (c * 4 + 2);
        m |= (v.w != 0 ? 1u : 0u) << (c * 4 + 3);
    }
    adjb[(size_t)row * 16 + w] = m;
}

// ---- projection: 8 rows/block, outputs HEAD-MAJOR gl/gr [b*8+hh][512][16] ----
__global__ __launch_bounds__(256) void proj_kernel(
    const float* __restrict__ h, const float* __restrict__ X,
    const float* __restrict__ Win,
    const float* __restrict__ Wl, const float* __restrict__ Wr,
    float* __restrict__ gl, float* __restrict__ gr)
{
    __shared__ __align__(16) float s_h[8][DH];
    const int bn0 = blockIdx.x * 8;
    const int b   = bn0 >> 9;
    const int n0  = bn0 & 511;
    const int t   = threadIdx.x;

    if (X) {
        if (t < DH) {
            const float w0 = Win[t], w1 = Win[DH + t];
#pragma unroll
            for (int r = 0; r < 8; ++r) {
                const float x0 = X[(bn0 + r) * 2 + 0];
                const float x1 = X[(bn0 + r) * 2 + 1];
                s_h[r][t] = x0 * w0 + x1 * w1;
            }
        }
    } else {
        for (int idx = t; idx < 8 * DH; idx += 256)
            s_h[idx >> 7][idx & 127] = h[(size_t)bn0 * DH + idx];
    }
    __syncthreads();

    const float* W = (t < DH) ? Wl : Wr;   // wave-uniform split
    float*       g = (t < DH) ? gl : gr;
    const int f128 = t & 127;
    float acc[8] = {};
    for (int k = 0; k < DH; k += 4) {
        const float w0 = W[(k + 0) * DH + f128];
        const float w1 = W[(k + 1) * DH + f128];
        const float w2 = W[(k + 2) * DH + f128];
        const float w3 = W[(k + 3) * DH + f128];
#pragma unroll
        for (int r = 0; r < 8; ++r) {
            const float4 hv = *(const float4*)&s_h[r][k];
            acc[r] += hv.x * w0 + hv.y * w1 + hv.z * w2 + hv.w * w3;
        }
    }
    const int hh = f128 >> 4, f = f128 & 15;
    float* dst = g + ((size_t)(b * NHEADS + hh) * NN + n0) * NHID + f;
#pragma unroll
    for (int r = 0; r < 8; ++r)
        dst[r * NHID] = acc[r];
}

// ---- flash-style attention: one block per (b, head, 64-row i-tile) ----
// 512 threads: il = t&31 (thread owns rows il and il+32), js = t>>5 (32-j slice).
// Each LDS j-read feeds TWO query rows. Online softmax over 4-j chunks keeps
// live state ~104 floats -> no scratch spills (R7's sc[64] blew the 128 budget).
__global__ __launch_bounds__(512) void attn_kernel(
    const float* __restrict__ gl, const float* __restrict__ gr,
    const uint32_t* __restrict__ adjb, const float* __restrict__ a_vec,
    float* __restrict__ h_out,
    const float* __restrict__ Wout, float* __restrict__ out)
{
    __shared__ __align__(16) float smem[19648];   // 78592 B
    float* s_gl  = smem;                // [512*16] = 8192
    float* s_gr  = smem + 8192;         // [512*16] = 8192
    float* s_acc = smem;                // alias (staging dead), [16*64*17]=17408
    float* s_m   = smem + 17408;        // [16*66]
    float* s_l   = smem + 18464;        // [16*66]
    float* s_M   = smem + 19520;        // [64]
    float* s_inv = smem + 19584;        // [64]

    const int blk = blockIdx.x;         // 256 = (b*8+hh)*8 + it
    const int it  = blk & 7;
    const int bh  = blk >> 3;
    const int b   = bh >> 3;
    const int hh  = bh & 7;
    const int i0  = it * ITILE;
    const int t   = threadIdx.x;
    const int il  = t & 31;
    const int js  = t >> 5;
    const int jbase = js * 32;

    {   // stage head planes: 2048 float4 each (512 rows x 16 fp32), coalesced
        const float4* pgl = (const float4*)(gl + (size_t)bh * NN * NHID);
        const float4* pgr = (const float4*)(gr + (size_t)bh * NN * NHID);
        float4* dl = (float4*)s_gl;
        float4* dr = (float4*)s_gr;
#pragma unroll
        for (int k = 0; k < 4; ++k) {           // 4 * 512 = 2048 float4
            dl[k * 512 + t] = pgl[k * 512 + t];
            dr[k * 512 + t] = pgr[k * 512 + t];
        }
    }
    const float4* a_g = (const float4*)a_vec;   // uniform -> SGPRs
    const float4 a4[4] = { a_g[0], a_g[1], a_g[2], a_g[3] };
    const uint32_t mask0 = adjb[((size_t)(b * NN + i0 + il))      * 16 + js];
    const uint32_t mask1 = adjb[((size_t)(b * NN + i0 + il + 32)) * 16 + js];
    __syncthreads();

    float gri0[16], gri1[16];
    {
        const float4* p0 = (const float4*)(s_gr + (i0 + il) * NHID);
        const float4* p1 = (const float4*)(s_gr + (i0 + il + 32) * NHID);
#pragma unroll
        for (int q = 0; q < 4; ++q) {
            const float4 v0 = p0[q], v1 = p1[q];
            gri0[4*q] = v0.x; gri0[4*q+1] = v0.y; gri0[4*q+2] = v0.z; gri0[4*q+3] = v0.w;
            gri1[4*q] = v1.x; gri1[4*q+1] = v1.y; gri1[4*q+2] = v1.z; gri1[4*q+3] = v1.w;
        }
    }

    float m0 = SENTINEL, m1 = SENTINEL, l0 = 0.f, l1 = 0.f;
    float acc0[16] = {}, acc1[16] = {};

    for (int jc = 0; jc < 32; jc += 4) {
        // scores for this 4-j chunk (2 rows)
        float sc0[4], sc1[4];
#pragma unroll
        for (int k = 0; k < 4; ++k) {
            const int jj = jc + k;
            const float4* pg = (const float4*)(s_gl + (jbase + jj) * NHID);
            float s0 = 0.f, s1 = 0.f;
#pragma unroll
            for (int q = 0; q < 4; ++q) {
                const float4 g = pg[q];     // half-wave-uniform -> broadcast
                const float4 av = a4[q];
                float v;
                v = g.x + gri0[4*q+0]; v = fmaxf(v, SLOPE * v); s0 += v * av.x;
                v = g.y + gri0[4*q+1]; v = fmaxf(v, SLOPE * v); s0 += v * av.y;
                v = g.z + gri0[4*q+2]; v = fmaxf(v, SLOPE * v); s0 += v * av.z;
                v = g.w + gri0[4*q+3]; v = fmaxf(v, SLOPE * v); s0 += v * av.w;
                v = g.x + gri1[4*q+0]; v = fmaxf(v, SLOPE * v); s1 += v * av.x;
                v = g.y + gri1[4*q+1]; v = fmaxf(v, SLOPE * v); s1 += v * av.y;
                v = g.z + gri1[4*q+2]; v = fmaxf(v, SLOPE * v); s1 += v * av.z;
                v = g.w + gri1[4*q+3]; v = fmaxf(v, SLOPE * v); s1 += v * av.w;
            }
            sc0[k] = ((mask0 >> jj) & 1u) ? s0 : SENTINEL;
            sc1[k] = ((mask1 >> jj) & 1u) ? s1 : SENTINEL;
        }
        // online-softmax merge of the chunk
        const float m40 = fmaxf(fmaxf(sc0[0], sc0[1]), fmaxf(sc0[2], sc0[3]));
        const float m41 = fmaxf(fmaxf(sc1[0], sc1[1]), fmaxf(sc1[2], sc1[3]));
        const float nm0 = fmaxf(m0, m40), nm1 = fmaxf(m1, m41);
        const float c0 = __expf(m0 - nm0), c1 = __expf(m1 - nm1);  // 1 if no new max
        l0 *= c0; l1 *= c1;
#pragma unroll
        for (int f = 0; f < 16; ++f) { acc0[f] *= c0; acc1[f] *= c1; }
#pragma unroll
        for (int k = 0; k < 4; ++k) {
            const float p0 = __expf(sc0[k] - nm0);   // masked -> 0
            const float p1 = __expf(sc1[k] - nm1);
            l0 += p0; l1 += p1;
            const float4* pg = (const float4*)(s_gr + (jbase + jc + k) * NHID);
#pragma unroll
            for (int q = 0; q < 4; ++q) {
                const float4 g = pg[q];     // broadcast
                acc0[4*q+0] += p0 * g.x; acc0[4*q+1] += p0 * g.y;
                acc0[4*q+2] += p0 * g.z; acc0[4*q+3] += p0 * g.w;
                acc1[4*q+0] += p1 * g.x; acc1[4*q+1] += p1 * g.y;
                acc1[4*q+2] += p1 * g.z; acc1[4*q+3] += p1 * g.w;
            }
        }
        m0 = nm0; m1 = nm1;
    }

    s_m[js * 66 + il]      = m0;  s_l[js * 66 + il]      = l0;
    s_m[js * 66 + il + 32] = m1;  s_l[js * 66 + il + 32] = l1;
    __syncthreads();                      // all staging reads retired here

    if (t < 64) {                         // per-i global max + denom
        float M = SENTINEL;
#pragma unroll
        for (int k = 0; k < 16; ++k) M = fmaxf(M, s_m[k * 66 + t]);
        float L = 0.f;
#pragma unroll
        for (int k = 0; k < 16; ++k) L += s_l[k * 66 + t] * __expf(s_m[k * 66 + t] - M);
        s_M[t]   = M;
        s_inv[t] = 1.f / L;
    }
    __syncthreads();

    {   // scaled partials into aliased scratch (stride 17 -> conflict-free)
        const float f0s = __expf(m0 - s_M[il])      * s_inv[il];   // all-masked slice -> 0
        const float f1s = __expf(m1 - s_M[il + 32]) * s_inv[il + 32];
        float* d0 = s_acc + (js * 64 + il) * 17;
        float* d1 = s_acc + (js * 64 + il + 32) * 17;
#pragma unroll
        for (int f = 0; f < 16; ++f) { d0[f] = acc0[f] * f0s; d1[f] = acc1[f] * f1s; }
    }
    __syncthreads();

    {   // final reduce: thread (i = t>>4 [+32], f = t&15)
        const int f = t & 15;
#pragma unroll
        for (int half = 0; half < 2; ++half) {
            const int i = (t >> 4) + half * 32;
            float o = 0.f;
#pragma unroll
            for (int k = 0; k < 16; ++k) o += s_acc[(k * 64 + i) * 17 + f];
            if (Wout) {                   // fused h @ W_out partial per head
                float v = o * Wout[hh * NHID + f];
#pragma unroll
                for (int off = 8; off; off >>= 1) v += __shfl_xor(v, off);
                if (f == 0) atomicAdd(out + b * NN + i0 + i, v);
            } else {
                h_out[((size_t)(b * NN + i0 + i)) * DH + hh * NHID + f] = o;
            }
        }
    }
}

extern "C" void kernel_launch(void* const* d_in, const int* in_sizes, int n_in,
                              void* d_out, int out_size, void* d_ws, size_t ws_size,
                              hipStream_t stream) {
    const float* X    = (const float*)d_in[0];   // [4,512,2]
    const int*   adj  = (const int*)  d_in[1];   // [4,512,512]
    const float* Win  = (const float*)d_in[2];   // [2,128]
    const float* Wl   = (const float*)d_in[3];   // [3,128,128]
    const float* Wr   = (const float*)d_in[4];   // [3,128,128]
    const float* Aa   = (const float*)d_in[5];   // [3,16]
    const float* Wout = (const float*)d_in[6];   // [128,1]
    float* out = (float*)d_out;                  // [4,512] fp32

    float*    ws   = (float*)d_ws;
    float*    h    = ws;                 // 1 MB
    float*    gl   = ws + 262144;        // 1 MB (head-major)
    float*    gr   = ws + 524288;        // 1 MB (head-major)
    uint32_t* adjb = (uint32_t*)(ws + 786432);   // 128 KB

    pack_adj_kernel<<<NB * NN / 16, 256, 0, stream>>>(adj, adjb);
    hipMemsetAsync(out, 0, (size_t)out_size * sizeof(float), stream);  // atomic target

    for (int l = 0; l < 3; ++l) {
        proj_kernel<<<NB * NN / 8, 256, 0, stream>>>(
            h, (l == 0) ? X : nullptr, Win,
            Wl + (size_t)l * DH * DH, Wr + (size_t)l * DH * DH, gl, gr);
        const bool last = (l == 2);
        attn_kernel<<<NB * NHEADS * (NN / ITILE), 512, 0, stream>>>(
            gl, gr, adjb, Aa + l * NHID, h,
            last ? Wout : nullptr, out);
    }
}